// Round 12
// baseline (154.298 us; speedup 1.0000x reference)
//
#include <hip/hip_runtime.h>

#define THREADS 256
#define BSH 11          // bucket shift: 2048 nodes per bucket
#define BSZ 2048
#define NBMAX 512
#define ST 8192         // scatter tile size (edges per block)
#define SCT 512         // scatter threads
#define EPT 16          // edges per thread in scatter (ST/SCT)
#define BT 1024         // bucket-kernel threads
#define CEPT 16         // records per thread in k_csr (covers C <= 16384)
#define SMASK 0xFFFFFu  // low 20 bits: src node id

// ===================== binned pipeline =====================

// Init per-bucket allocation cursors: gcur[j] = j*C.
__global__ void k_init(unsigned* __restrict__ gcur, unsigned C, int NB) {
    int t = threadIdx.x;
    if (t < NB) gcur[t] = (unsigned)t * C;
}

// Tile-local counting sort + coalesced write-out into fixed-capacity buckets.
// packed record: src(20b) | dst_local(11b)<<20.  (verified r10/r11)
__global__ void __launch_bounds__(SCT)
k_scatter(const int* __restrict__ src,
          const int* __restrict__ dst, int E,
          unsigned* __restrict__ gcur,
          unsigned* __restrict__ packed, unsigned C, int NB) {
    __shared__ unsigned tcnt[NBMAX];
    __shared__ unsigned toff[NBMAX];
    __shared__ unsigned gb[NBMAX];
    __shared__ unsigned sh[NBMAX];
    __shared__ unsigned sorted[ST];
    __shared__ unsigned short jarr[ST];

    int tid = threadIdx.x;
    int lo = blockIdx.x * ST;
    int cnt = E - lo; if (cnt > ST) cnt = ST;

    tcnt[tid] = 0u;            // SCT==512==NBMAX
    __syncthreads();

    unsigned jreg[EPT], rreg[EPT], rank[EPT];
    #pragma unroll
    for (int kk = 0; kk < EPT / 4; ++kk) {
        int g = kk * SCT + tid;
        int base = g * 4;
        if (base + 3 < cnt) {
            int4 d4 = *(const int4*)(dst + lo + base);
            int4 s4 = *(const int4*)(src + lo + base);
            unsigned j0 = (unsigned)d4.x >> BSH;
            unsigned j1 = (unsigned)d4.y >> BSH;
            unsigned j2 = (unsigned)d4.z >> BSH;
            unsigned j3 = (unsigned)d4.w >> BSH;
            jreg[kk*4+0] = j0; rreg[kk*4+0] = (unsigned)s4.x | (((unsigned)d4.x & (BSZ-1)) << 20);
            jreg[kk*4+1] = j1; rreg[kk*4+1] = (unsigned)s4.y | (((unsigned)d4.y & (BSZ-1)) << 20);
            jreg[kk*4+2] = j2; rreg[kk*4+2] = (unsigned)s4.z | (((unsigned)d4.z & (BSZ-1)) << 20);
            jreg[kk*4+3] = j3; rreg[kk*4+3] = (unsigned)s4.w | (((unsigned)d4.w & (BSZ-1)) << 20);
            rank[kk*4+0] = atomicAdd(&tcnt[j0], 1u);
            rank[kk*4+1] = atomicAdd(&tcnt[j1], 1u);
            rank[kk*4+2] = atomicAdd(&tcnt[j2], 1u);
            rank[kk*4+3] = atomicAdd(&tcnt[j3], 1u);
        } else {
            #pragma unroll
            for (int c = 0; c < 4; ++c) {
                int idx = base + c;
                if (idx < cnt) {
                    int d = dst[lo + idx];
                    unsigned jj = (unsigned)d >> BSH;
                    jreg[kk*4+c] = jj;
                    rreg[kk*4+c] = (unsigned)src[lo + idx] | (((unsigned)d & (BSZ-1)) << 20);
                    rank[kk*4+c] = atomicAdd(&tcnt[jj], 1u);
                } else {
                    jreg[kk*4+c] = ~0u;
                }
            }
        }
    }
    __syncthreads();

    unsigned v = tcnt[tid];
    sh[tid] = v;
    __syncthreads();
    for (int off = 1; off < NBMAX; off <<= 1) {
        unsigned t = (tid >= off) ? sh[tid - off] : 0u;
        __syncthreads();
        sh[tid] += t;
        __syncthreads();
    }
    {
        unsigned excl = sh[tid] - v;
        toff[tid] = excl;
        if (v) gb[tid] = atomicAdd(&gcur[tid], v);
    }
    __syncthreads();

    #pragma unroll
    for (int k = 0; k < EPT; ++k) {
        unsigned jj = jreg[k];
        if (jj != ~0u) {
            unsigned p = toff[jj] + rank[k];
            sorted[p] = rreg[k];
            jarr[p] = (unsigned short)jj;
        }
    }
    __syncthreads();

    for (int p = tid; p < cnt; p += SCT) {
        unsigned jj = jarr[p];
        unsigned pos = gb[jj] + ((unsigned)p - toff[jj]);
        if (pos < (jj + 1u) * C) packed[pos] = sorted[p];
    }
}

// Per-bucket CSR build: histogram(dl) = degree -> dinv,y ; shfl-scan ->
// rowptr ; atomic rank -> place src into CSR order. Replaces k_deg.
__global__ void __launch_bounds__(BT)
k_csr(const unsigned* __restrict__ packed,
      const unsigned* __restrict__ gcur, unsigned C,
      const float* __restrict__ x,
      unsigned* __restrict__ csr, unsigned* __restrict__ rowptr,
      float* __restrict__ dinv, float* __restrict__ y, int N) {
    int j = blockIdx.x;
    __shared__ unsigned cnt[BSZ];
    __shared__ unsigned excl[BSZ];
    __shared__ unsigned wsum[16];
    unsigned tid = threadIdx.x;

    for (int t = tid; t < BSZ; t += BT) cnt[t] = 0u;
    __syncthreads();

    unsigned e0 = (unsigned)j * C;                    // C%4==0 -> 16B aligned
    unsigned e1 = gcur[j]; if (e1 > e0 + C) e1 = e0 + C;
    const unsigned n = e1 - e0;

    unsigned dl[CEPT], sr[CEPT], rk[CEPT];
    #pragma unroll
    for (int kk = 0; kk < CEPT / 4; ++kk) {
        unsigned b4 = ((unsigned)kk * BT + tid) * 4u;
        if (b4 + 3u < n) {
            uint4 a = *(const uint4*)(packed + e0 + (size_t)b4);
            dl[kk*4+0] = a.x >> 20; sr[kk*4+0] = a.x & SMASK;
            dl[kk*4+1] = a.y >> 20; sr[kk*4+1] = a.y & SMASK;
            dl[kk*4+2] = a.z >> 20; sr[kk*4+2] = a.z & SMASK;
            dl[kk*4+3] = a.w >> 20; sr[kk*4+3] = a.w & SMASK;
            rk[kk*4+0] = atomicAdd(&cnt[dl[kk*4+0]], 1u);
            rk[kk*4+1] = atomicAdd(&cnt[dl[kk*4+1]], 1u);
            rk[kk*4+2] = atomicAdd(&cnt[dl[kk*4+2]], 1u);
            rk[kk*4+3] = atomicAdd(&cnt[dl[kk*4+3]], 1u);
        } else {
            #pragma unroll
            for (int c = 0; c < 4; ++c) {
                unsigned idx = b4 + c;
                if (idx < n) {
                    unsigned p = packed[e0 + idx];
                    dl[kk*4+c] = p >> 20; sr[kk*4+c] = p & SMASK;
                    rk[kk*4+c] = atomicAdd(&cnt[p >> 20], 1u);
                } else {
                    dl[kk*4+c] = ~0u;
                }
            }
        }
    }
    __syncthreads();

    // exclusive scan of cnt[0..BSZ): thread owns (2t, 2t+1)
    {
        unsigned s0 = cnt[2u*tid], s1 = cnt[2u*tid + 1u];
        unsigned T = s0 + s1;
        unsigned incl = T;
        #pragma unroll
        for (int off = 1; off < 64; off <<= 1) {
            unsigned u = __shfl_up(incl, off, 64);
            if ((tid & 63u) >= (unsigned)off) incl += u;
        }
        unsigned wid = tid >> 6;                  // 16 waves
        if ((tid & 63u) == 63u) wsum[wid] = incl;
        __syncthreads();
        if (tid < 16u) {
            unsigned w = wsum[tid];
            unsigned wi = w;
            #pragma unroll
            for (int off = 1; off < 16; off <<= 1) {
                unsigned u = __shfl_up(wi, off, 64);
                if (tid >= (unsigned)off) wi += u;
            }
            wsum[tid] = wi;                       // inclusive over waves
        }
        __syncthreads();
        unsigned wbase = (wid == 0u) ? 0u : wsum[wid - 1u];
        unsigned te = wbase + incl - T;
        excl[2u*tid] = te;
        excl[2u*tid + 1u] = te + s0;
    }
    __syncthreads();

    // place sources into CSR order
    #pragma unroll
    for (int k = 0; k < CEPT; ++k) {
        if (dl[k] != ~0u) csr[e0 + excl[dl[k]] + rk[k]] = sr[k];
    }

    // epilogue: rowptr, dinv, y
    int base = j << BSH;
    for (int t = tid; t < BSZ; t += BT) {
        int v = base + t;
        if (v < N) {
            float d = rsqrtf((float)cnt[t] + 1.0f);
            dinv[v] = d;
            y[v] = x[v] * d;
            rowptr[v] = e0 + excl[t];
        }
    }
}

// Layer-1 segment-sum (atomic-free) + fused MLP -> zy.
__global__ void __launch_bounds__(BT)
k2_acc1(const unsigned* __restrict__ csr,
        const unsigned* __restrict__ gcur, unsigned C,
        const unsigned* __restrict__ rowptr,
        const float* __restrict__ y, const float* __restrict__ dinv,
        const float* __restrict__ W1, const float* __restrict__ b1,
        const float* __restrict__ W2,
        float* __restrict__ zy, int N, int F) {
    int j = blockIdx.x;
    __shared__ float w1s[64], b1s[64], w2s[64];
    if (threadIdx.x < (unsigned)F) {
        w1s[threadIdx.x] = W1[threadIdx.x];
        b1s[threadIdx.x] = b1[threadIdx.x];
        w2s[threadIdx.x] = W2[threadIdx.x];
    }
    __syncthreads();
    unsigned e0 = (unsigned)j * C;
    unsigned e1 = gcur[j]; if (e1 > e0 + C) e1 = e0 + C;
    int base = j << BSH;
    for (int t = threadIdx.x; t < BSZ; t += BT) {
        int v = base + t;
        if (v < N) {
            unsigned lo = rowptr[v];
            unsigned hi = (t == BSZ - 1 || v + 1 >= N) ? e1 : rowptr[v + 1];
            float s = 0.f;
            for (unsigned e = lo; e < hi; ++e) s += y[csr[e]];
            float d = dinv[v];
            float agg = d * (s + y[v]);
            float z = 0.f;
            for (int f = 0; f < F; ++f) {
                float h = fmaf(w1s[f], agg, b1s[f]);
                h = fmaxf(h, 0.f);
                z = fmaf(h, w2s[f], z);
            }
            zy[v] = z * d;
        }
    }
}

// Layer-2 segment-sum (atomic-free) -> out.
__global__ void __launch_bounds__(BT)
k2_out(const unsigned* __restrict__ csr,
       const unsigned* __restrict__ gcur, unsigned C,
       const unsigned* __restrict__ rowptr,
       const float* __restrict__ zy, const float* __restrict__ dinv,
       const float* __restrict__ b2,
       float* __restrict__ out, int N) {
    int j = blockIdx.x;
    unsigned e0 = (unsigned)j * C;
    unsigned e1 = gcur[j]; if (e1 > e0 + C) e1 = e0 + C;
    int base = j << BSH;
    float bb = b2[0];
    for (int t = threadIdx.x; t < BSZ; t += BT) {
        int v = base + t;
        if (v < N) {
            unsigned lo = rowptr[v];
            unsigned hi = (t == BSZ - 1 || v + 1 >= N) ? e1 : rowptr[v + 1];
            float s = 0.f;
            for (unsigned e = lo; e < hi; ++e) s += zy[csr[e]];
            out[v] = fmaf(dinv[v], s + zy[v], bb);
        }
    }
}

// ---- backup bucket kernels (verified r10 path) ----

__global__ void k_deg(const unsigned* __restrict__ packed,
                      const unsigned* __restrict__ gcur, unsigned C,
                      const float* __restrict__ x,
                      float* __restrict__ dinv, float* __restrict__ y, int N) {
    int j = blockIdx.x;
    __shared__ unsigned cntl[BSZ];
    for (int t = threadIdx.x; t < BSZ; t += BT) cntl[t] = 0u;
    __syncthreads();
    unsigned e0 = (unsigned)j * C;
    unsigned e1 = gcur[j]; if (e1 > e0 + C) e1 = e0 + C;
    unsigned tid = threadIdx.x;
    unsigned nv4 = (e1 - e0) >> 2;
    for (unsigned g = tid; g < nv4; g += BT) {
        uint4 a = *(const uint4*)(packed + e0 + (size_t)g * 4u);
        atomicAdd(&cntl[a.x >> 20], 1u);
        atomicAdd(&cntl[a.y >> 20], 1u);
        atomicAdd(&cntl[a.z >> 20], 1u);
        atomicAdd(&cntl[a.w >> 20], 1u);
    }
    for (unsigned e = e0 + nv4 * 4u + tid; e < e1; e += BT)
        atomicAdd(&cntl[packed[e] >> 20], 1u);
    __syncthreads();
    int base = j << BSH;
    for (int t = threadIdx.x; t < BSZ; t += BT) {
        int v = base + t;
        if (v < N) {
            float d = rsqrtf((float)cntl[t] + 1.0f);
            dinv[v] = d;
            y[v] = x[v] * d;
        }
    }
}

__global__ void k_acc1(const unsigned* __restrict__ packed,
                       const unsigned* __restrict__ gcur, unsigned C,
                       const float* __restrict__ y,
                       const float* __restrict__ dinv,
                       const float* __restrict__ W1,
                       const float* __restrict__ b1,
                       const float* __restrict__ W2,
                       float* __restrict__ zy, int N, int F) {
    int j = blockIdx.x;
    __shared__ float acc[BSZ];
    __shared__ float w1s[64], b1s[64], w2s[64];
    for (int t = threadIdx.x; t < BSZ; t += BT) acc[t] = 0.f;
    if (threadIdx.x < (unsigned)F) {
        w1s[threadIdx.x] = W1[threadIdx.x];
        b1s[threadIdx.x] = b1[threadIdx.x];
        w2s[threadIdx.x] = W2[threadIdx.x];
    }
    __syncthreads();
    unsigned e0 = (unsigned)j * C;
    unsigned e1 = gcur[j]; if (e1 > e0 + C) e1 = e0 + C;
    unsigned tid = threadIdx.x;
    unsigned nv4 = (e1 - e0) >> 2;
    for (unsigned g = tid; g < nv4; g += BT) {
        uint4 a = *(const uint4*)(packed + e0 + (size_t)g * 4u);
        float v0 = y[a.x & SMASK], v1 = y[a.y & SMASK];
        float v2 = y[a.z & SMASK], v3 = y[a.w & SMASK];
        atomicAdd(&acc[a.x >> 20], v0);
        atomicAdd(&acc[a.y >> 20], v1);
        atomicAdd(&acc[a.z >> 20], v2);
        atomicAdd(&acc[a.w >> 20], v3);
    }
    for (unsigned e = e0 + nv4 * 4u + tid; e < e1; e += BT) {
        unsigned p = packed[e];
        atomicAdd(&acc[p >> 20], y[p & SMASK]);
    }
    __syncthreads();
    int base = j << BSH;
    for (int t = threadIdx.x; t < BSZ; t += BT) {
        int v = base + t;
        if (v < N) {
            float d = dinv[v];
            float agg = d * (acc[t] + y[v]);
            float z = 0.f;
            for (int f = 0; f < F; ++f) {
                float h = fmaf(w1s[f], agg, b1s[f]);
                h = fmaxf(h, 0.f);
                z = fmaf(h, w2s[f], z);
            }
            zy[v] = z * d;
        }
    }
}

__global__ void k_out(const unsigned* __restrict__ packed,
                      const unsigned* __restrict__ gcur, unsigned C,
                      const float* __restrict__ zy,
                      const float* __restrict__ dinv,
                      const float* __restrict__ b2,
                      float* __restrict__ out, int N) {
    int j = blockIdx.x;
    __shared__ float acc[BSZ];
    for (int t = threadIdx.x; t < BSZ; t += BT) acc[t] = 0.f;
    __syncthreads();
    unsigned e0 = (unsigned)j * C;
    unsigned e1 = gcur[j]; if (e1 > e0 + C) e1 = e0 + C;
    unsigned tid = threadIdx.x;
    unsigned nv4 = (e1 - e0) >> 2;
    for (unsigned g = tid; g < nv4; g += BT) {
        uint4 a = *(const uint4*)(packed + e0 + (size_t)g * 4u);
        float v0 = zy[a.x & SMASK], v1 = zy[a.y & SMASK];
        float v2 = zy[a.z & SMASK], v3 = zy[a.w & SMASK];
        atomicAdd(&acc[a.x >> 20], v0);
        atomicAdd(&acc[a.y >> 20], v1);
        atomicAdd(&acc[a.z >> 20], v2);
        atomicAdd(&acc[a.w >> 20], v3);
    }
    for (unsigned e = e0 + nv4 * 4u + tid; e < e1; e += BT) {
        unsigned p = packed[e];
        atomicAdd(&acc[p >> 20], zy[p & SMASK]);
    }
    __syncthreads();
    int base = j << BSH;
    for (int t = threadIdx.x; t < BSZ; t += BT) {
        int v = base + t;
        if (v < N)
            out[v] = fmaf(dinv[v], acc[t] + zy[v], b2[0]);
    }
}

// ===================== fallback: global-atomic pipeline ==================

__global__ void f_zero3(float* __restrict__ a, float* __restrict__ b,
                        float* __restrict__ c, int N) {
    int i = blockIdx.x * blockDim.x + threadIdx.x;
    int stride = gridDim.x * blockDim.x;
    for (int v = i; v < N; v += stride) { a[v] = 0.f; b[v] = 0.f; c[v] = 0.f; }
}
__global__ void f_deg(const int* __restrict__ dst, int E, float* __restrict__ degf) {
    int i = blockIdx.x * blockDim.x + threadIdx.x;
    int stride = gridDim.x * blockDim.x;
    for (int e = i; e < E; e += stride) atomicAdd(&degf[dst[e]], 1.0f);
}
__global__ void f_dinv(float* __restrict__ d, int N) {
    int v = blockIdx.x * blockDim.x + threadIdx.x;
    if (v < N) d[v] = rsqrtf(d[v] + 1.0f);
}
__global__ void f_edge1(const int* __restrict__ src, const int* __restrict__ dst,
                        const float* __restrict__ x, const float* __restrict__ dinv,
                        float* __restrict__ acc1, int E) {
    int i = blockIdx.x * blockDim.x + threadIdx.x;
    int stride = gridDim.x * blockDim.x;
    for (int e = i; e < E; e += stride) {
        int s = src[e];
        atomicAdd(&acc1[dst[e]], x[s] * dinv[s]);
    }
}
__global__ void f_node2(const float* __restrict__ dinv, const float* __restrict__ acc1,
                        const float* __restrict__ x, const float* __restrict__ W1,
                        const float* __restrict__ b1, const float* __restrict__ W2,
                        float* __restrict__ zy, int N, int F) {
    int v = blockIdx.x * blockDim.x + threadIdx.x;
    if (v < N) {
        float d = dinv[v];
        float agg = d * (acc1[v] + x[v] * d);
        float z = 0.f;
        for (int f = 0; f < F; ++f) {
            float h = fmaf(W1[f], agg, b1[f]);
            h = h > 0.f ? h : 0.f;
            z = fmaf(h, W2[f], z);
        }
        zy[v] = z * d;
    }
}
__global__ void f_edge2(const int* __restrict__ src, const int* __restrict__ dst,
                        const float* __restrict__ zy, float* __restrict__ out, int E) {
    int i = blockIdx.x * blockDim.x + threadIdx.x;
    int stride = gridDim.x * blockDim.x;
    for (int e = i; e < E; e += stride) atomicAdd(&out[dst[e]], zy[src[e]]);
}
__global__ void f_node3(const float* __restrict__ dinv, const float* __restrict__ zy,
                        const float* __restrict__ b2, float* __restrict__ out, int N) {
    int v = blockIdx.x * blockDim.x + threadIdx.x;
    if (v < N) out[v] = fmaf(dinv[v], out[v] + zy[v], b2[0]);
}

// ===================== launch ===========================================

extern "C" void kernel_launch(void* const* d_in, const int* in_sizes, int n_in,
                              void* d_out, int out_size, void* d_ws, size_t ws_size,
                              hipStream_t stream) {
    const float* x  = (const float*)d_in[0];
    const int*   ei = (const int*)d_in[1];   // harness passes integers as int32
    const float* W1 = (const float*)d_in[2];
    const float* b1 = (const float*)d_in[3];
    const float* W2 = (const float*)d_in[4];
    const float* b2 = (const float*)d_in[5];
    float* out = (float*)d_out;

    const int N = in_sizes[0];
    const int E = in_sizes[1] / 2;
    const int F = in_sizes[2];

    const int* src = ei;
    const int* dst = ei + E;

    const int NB = (N + BSZ - 1) >> BSH;

    // fixed per-bucket capacity: mean + ~12.5% + 1024 slack, multiple of 4.
    unsigned mean = (unsigned)(E / (NB > 0 ? NB : 1));
    unsigned C = (mean + mean / 8u + 1024u + 3u) & ~3u;

    // workspace: [packed NB*C | csr NB*C | gcur NBMAX | rowptr N | dinv N | y N | zy N]
    size_t off_packed = 0;
    size_t off_csr    = (off_packed + (size_t)NB * C * 4 + 15) & ~(size_t)15;
    size_t off_gc     = (off_csr + (size_t)NB * C * 4 + 15) & ~(size_t)15;
    size_t off_rp     = (off_gc + (size_t)NBMAX * 4 + 15) & ~(size_t)15;
    size_t off_dinv   = off_rp + (size_t)N * 4;
    size_t off_y      = off_dinv + (size_t)N * 4;
    size_t off_zy     = off_y + (size_t)N * 4;
    size_t need       = off_zy + (size_t)N * 4;

    bool ok = (ws_size >= need) && (NB >= 1) && (NB <= NBMAX) &&
              (N <= (1 << 20)) && (F <= 64) && (E > 0);

    char* ws = (char*)d_ws;
    if (ok) {
        unsigned* packed = (unsigned*)(ws + off_packed);
        unsigned* csr    = (unsigned*)(ws + off_csr);
        unsigned* gcur   = (unsigned*)(ws + off_gc);
        unsigned* rowptr = (unsigned*)(ws + off_rp);
        float*    dinv   = (float*)(ws + off_dinv);
        float*    y      = (float*)(ws + off_y);
        float*    zy     = (float*)(ws + off_zy);

        int scatBlocks = (E + ST - 1) / ST;

        k_init   <<<1, NBMAX, 0, stream>>>(gcur, C, NB);
        k_scatter<<<scatBlocks, SCT, 0, stream>>>(src, dst, E, gcur, packed, C, NB);

        if (C <= (unsigned)(CEPT * BT)) {
            // CSR path: atomic-free accumulate passes
            k_csr  <<<NB, BT, 0, stream>>>(packed, gcur, C, x, csr, rowptr, dinv, y, N);
            k2_acc1<<<NB, BT, 0, stream>>>(csr, gcur, C, rowptr, y, dinv, W1, b1, W2, zy, N, F);
            k2_out <<<NB, BT, 0, stream>>>(csr, gcur, C, rowptr, zy, dinv, b2, out, N);
        } else {
            // verified r10 path
            k_deg  <<<NB, BT, 0, stream>>>(packed, gcur, C, x, dinv, y, N);
            k_acc1 <<<NB, BT, 0, stream>>>(packed, gcur, C, y, dinv, W1, b1, W2, zy, N, F);
            k_out  <<<NB, BT, 0, stream>>>(packed, gcur, C, zy, dinv, b2, out, N);
        }
    } else {
        // fallback: verified global-atomic path (needs 12 MB)
        float* dinv = (float*)(ws);
        float* acc1 = (float*)(ws + (size_t)N * 4);
        float* zy   = (float*)(ws + (size_t)N * 8);
        int nodeBlocks = (N + THREADS - 1) / THREADS;
        int edgeBlocks = (E + THREADS - 1) / THREADS;
        if (edgeBlocks > 2048) edgeBlocks = 2048;
        f_zero3<<<2048, THREADS, 0, stream>>>(dinv, acc1, out, N);
        f_deg  <<<edgeBlocks, THREADS, 0, stream>>>(dst, E, dinv);
        f_dinv <<<nodeBlocks, THREADS, 0, stream>>>(dinv, N);
        f_edge1<<<edgeBlocks, THREADS, 0, stream>>>(src, dst, x, dinv, acc1, E);
        f_node2<<<nodeBlocks, THREADS, 0, stream>>>(dinv, acc1, x, W1, b1, W2, zy, N, F);
        f_edge2<<<edgeBlocks, THREADS, 0, stream>>>(src, dst, zy, out, E);
        f_node3<<<nodeBlocks, THREADS, 0, stream>>>(dinv, zy, b2, out, N);
    }
}

// Round 13
// 123.146 us; speedup vs baseline: 1.2530x; 1.2530x over previous
//
#include <hip/hip_runtime.h>

#define THREADS 256
#define BSH 11          // bucket shift: 2048 nodes per bucket
#define BSZ 2048
#define NBMAX 512
#define ST 8192         // scatter tile size (edges per block)
#define SCT 512         // scatter threads
#define EPT 16          // edges per thread in scatter (ST/SCT)
#define BT 1024         // bucket-kernel threads
#define SMASK 0xFFFFFu  // low 20 bits: src node id

// ===================== binned pipeline =====================

// Init per-bucket allocation cursors: gcur[j] = j*C.
__global__ void k_init(unsigned* __restrict__ gcur, unsigned C, int NB) {
    int t = threadIdx.x;
    if (t < NB) gcur[t] = (unsigned)t * C;
}

// Direct scatter into fixed-capacity buckets. Per tile: LDS count+rank ->
// reserve global run per bucket -> write records directly at gb+rank.
// Runs are ~ST/NBMAX = 16 records = one 64B line -> L2 merges the writes.
// packed record: src(20b) | dst_local(11b)<<20.
__global__ void __launch_bounds__(SCT)
k_scatter(const int* __restrict__ src,
          const int* __restrict__ dst, int E,
          unsigned* __restrict__ gcur,
          unsigned* __restrict__ packed, unsigned C, int NB) {
    __shared__ unsigned tcnt[NBMAX];
    __shared__ unsigned gb[NBMAX];

    int tid = threadIdx.x;
    int lo = blockIdx.x * ST;
    int cnt = E - lo; if (cnt > ST) cnt = ST;   // >0 by grid sizing

    tcnt[tid] = 0u;            // SCT==512==NBMAX
    __syncthreads();

    unsigned jreg[EPT], rreg[EPT], rank[EPT];
    // vectorized load: int4 groups of 4 consecutive edges (lo is 16B-aligned)
    #pragma unroll
    for (int kk = 0; kk < EPT / 4; ++kk) {
        int g = kk * SCT + tid;          // group index within tile
        int base = g * 4;
        if (base + 3 < cnt) {
            int4 d4 = *(const int4*)(dst + lo + base);
            int4 s4 = *(const int4*)(src + lo + base);
            unsigned j0 = (unsigned)d4.x >> BSH;
            unsigned j1 = (unsigned)d4.y >> BSH;
            unsigned j2 = (unsigned)d4.z >> BSH;
            unsigned j3 = (unsigned)d4.w >> BSH;
            jreg[kk*4+0] = j0; rreg[kk*4+0] = (unsigned)s4.x | (((unsigned)d4.x & (BSZ-1)) << 20);
            jreg[kk*4+1] = j1; rreg[kk*4+1] = (unsigned)s4.y | (((unsigned)d4.y & (BSZ-1)) << 20);
            jreg[kk*4+2] = j2; rreg[kk*4+2] = (unsigned)s4.z | (((unsigned)d4.z & (BSZ-1)) << 20);
            jreg[kk*4+3] = j3; rreg[kk*4+3] = (unsigned)s4.w | (((unsigned)d4.w & (BSZ-1)) << 20);
            rank[kk*4+0] = atomicAdd(&tcnt[j0], 1u);
            rank[kk*4+1] = atomicAdd(&tcnt[j1], 1u);
            rank[kk*4+2] = atomicAdd(&tcnt[j2], 1u);
            rank[kk*4+3] = atomicAdd(&tcnt[j3], 1u);
        } else {
            #pragma unroll
            for (int c = 0; c < 4; ++c) {
                int idx = base + c;
                if (idx < cnt) {
                    int d = dst[lo + idx];
                    unsigned jj = (unsigned)d >> BSH;
                    jreg[kk*4+c] = jj;
                    rreg[kk*4+c] = (unsigned)src[lo + idx] | (((unsigned)d & (BSZ-1)) << 20);
                    rank[kk*4+c] = atomicAdd(&tcnt[jj], 1u);
                } else {
                    jreg[kk*4+c] = ~0u;
                }
            }
        }
    }
    __syncthreads();

    // reserve a contiguous global run per bucket
    {
        unsigned v = tcnt[tid];
        if (v) gb[tid] = atomicAdd(&gcur[tid], v);
    }
    __syncthreads();

    // direct write: record -> packed[gb[jj] + rank]  (run covers full lines)
    #pragma unroll
    for (int k = 0; k < EPT; ++k) {
        unsigned jj = jreg[k];
        if (jj != ~0u) {
            unsigned pos = gb[jj] + rank[k];
            if (pos < (jj + 1u) * C) packed[pos] = rreg[k];  // drop-guard
        }
    }
}

// Per-bucket degree count in LDS -> dinv & y = x*dinv (exclusive node range).
__global__ void k_deg(const unsigned* __restrict__ packed,
                      const unsigned* __restrict__ gcur, unsigned C,
                      const float* __restrict__ x,
                      float* __restrict__ dinv, float* __restrict__ y, int N) {
    int j = blockIdx.x;
    __shared__ unsigned cntl[BSZ];
    for (int t = threadIdx.x; t < BSZ; t += BT) cntl[t] = 0u;
    __syncthreads();
    unsigned e0 = (unsigned)j * C;                    // C%4==0 -> 16B aligned
    unsigned e1 = gcur[j]; if (e1 > e0 + C) e1 = e0 + C;
    unsigned tid = threadIdx.x;
    unsigned nv4 = (e1 - e0) >> 2;
    unsigned g = tid;
    for (; g + BT < nv4; g += 2u * BT) {
        uint4 a = *(const uint4*)(packed + e0 + (size_t)g * 4u);
        uint4 b = *(const uint4*)(packed + e0 + (size_t)(g + BT) * 4u);
        atomicAdd(&cntl[a.x >> 20], 1u);
        atomicAdd(&cntl[a.y >> 20], 1u);
        atomicAdd(&cntl[a.z >> 20], 1u);
        atomicAdd(&cntl[a.w >> 20], 1u);
        atomicAdd(&cntl[b.x >> 20], 1u);
        atomicAdd(&cntl[b.y >> 20], 1u);
        atomicAdd(&cntl[b.z >> 20], 1u);
        atomicAdd(&cntl[b.w >> 20], 1u);
    }
    for (; g < nv4; g += BT) {
        uint4 a = *(const uint4*)(packed + e0 + (size_t)g * 4u);
        atomicAdd(&cntl[a.x >> 20], 1u);
        atomicAdd(&cntl[a.y >> 20], 1u);
        atomicAdd(&cntl[a.z >> 20], 1u);
        atomicAdd(&cntl[a.w >> 20], 1u);
    }
    for (unsigned e = e0 + nv4 * 4u + tid; e < e1; e += BT)
        atomicAdd(&cntl[packed[e] >> 20], 1u);
    __syncthreads();
    int base = j << BSH;
    for (int t = threadIdx.x; t < BSZ; t += BT) {
        int v = base + t;
        if (v < N) {
            float d = rsqrtf((float)cntl[t] + 1.0f);
            dinv[v] = d;
            y[v] = x[v] * d;
        }
    }
}

// Layer-1 aggregate (LDS) + fused per-node MLP -> zy = z*dinv.
__global__ void k_acc1(const unsigned* __restrict__ packed,
                       const unsigned* __restrict__ gcur, unsigned C,
                       const float* __restrict__ y,
                       const float* __restrict__ dinv,
                       const float* __restrict__ W1,
                       const float* __restrict__ b1,
                       const float* __restrict__ W2,
                       float* __restrict__ zy, int N, int F) {
    int j = blockIdx.x;
    __shared__ float acc[BSZ];
    __shared__ float w1s[64], b1s[64], w2s[64];
    for (int t = threadIdx.x; t < BSZ; t += BT) acc[t] = 0.f;
    if (threadIdx.x < (unsigned)F) {
        w1s[threadIdx.x] = W1[threadIdx.x];
        b1s[threadIdx.x] = b1[threadIdx.x];
        w2s[threadIdx.x] = W2[threadIdx.x];
    }
    __syncthreads();
    unsigned e0 = (unsigned)j * C;
    unsigned e1 = gcur[j]; if (e1 > e0 + C) e1 = e0 + C;
    unsigned tid = threadIdx.x;
    unsigned nv4 = (e1 - e0) >> 2;
    unsigned g = tid;
    for (; g + BT < nv4; g += 2u * BT) {
        uint4 a = *(const uint4*)(packed + e0 + (size_t)g * 4u);
        uint4 b = *(const uint4*)(packed + e0 + (size_t)(g + BT) * 4u);
        float v0 = y[a.x & SMASK], v1 = y[a.y & SMASK];
        float v2 = y[a.z & SMASK], v3 = y[a.w & SMASK];
        float v4 = y[b.x & SMASK], v5 = y[b.y & SMASK];
        float v6 = y[b.z & SMASK], v7 = y[b.w & SMASK];
        atomicAdd(&acc[a.x >> 20], v0);
        atomicAdd(&acc[a.y >> 20], v1);
        atomicAdd(&acc[a.z >> 20], v2);
        atomicAdd(&acc[a.w >> 20], v3);
        atomicAdd(&acc[b.x >> 20], v4);
        atomicAdd(&acc[b.y >> 20], v5);
        atomicAdd(&acc[b.z >> 20], v6);
        atomicAdd(&acc[b.w >> 20], v7);
    }
    for (; g < nv4; g += BT) {
        uint4 a = *(const uint4*)(packed + e0 + (size_t)g * 4u);
        float v0 = y[a.x & SMASK], v1 = y[a.y & SMASK];
        float v2 = y[a.z & SMASK], v3 = y[a.w & SMASK];
        atomicAdd(&acc[a.x >> 20], v0);
        atomicAdd(&acc[a.y >> 20], v1);
        atomicAdd(&acc[a.z >> 20], v2);
        atomicAdd(&acc[a.w >> 20], v3);
    }
    for (unsigned e = e0 + nv4 * 4u + tid; e < e1; e += BT) {
        unsigned p = packed[e];
        atomicAdd(&acc[p >> 20], y[p & SMASK]);
    }
    __syncthreads();
    int base = j << BSH;
    for (int t = threadIdx.x; t < BSZ; t += BT) {
        int v = base + t;
        if (v < N) {
            float d = dinv[v];
            float agg = d * (acc[t] + y[v]);
            float z = 0.f;
            for (int f = 0; f < F; ++f) {
                float h = fmaf(w1s[f], agg, b1s[f]);
                h = fmaxf(h, 0.f);
                z = fmaf(h, w2s[f], z);
            }
            zy[v] = z * d;
        }
    }
}

// Layer-2 aggregate (LDS) -> out = dinv*(acc + zy) + b2.
__global__ void k_out(const unsigned* __restrict__ packed,
                      const unsigned* __restrict__ gcur, unsigned C,
                      const float* __restrict__ zy,
                      const float* __restrict__ dinv,
                      const float* __restrict__ b2,
                      float* __restrict__ out, int N) {
    int j = blockIdx.x;
    __shared__ float acc[BSZ];
    for (int t = threadIdx.x; t < BSZ; t += BT) acc[t] = 0.f;
    __syncthreads();
    unsigned e0 = (unsigned)j * C;
    unsigned e1 = gcur[j]; if (e1 > e0 + C) e1 = e0 + C;
    unsigned tid = threadIdx.x;
    unsigned nv4 = (e1 - e0) >> 2;
    unsigned g = tid;
    for (; g + BT < nv4; g += 2u * BT) {
        uint4 a = *(const uint4*)(packed + e0 + (size_t)g * 4u);
        uint4 b = *(const uint4*)(packed + e0 + (size_t)(g + BT) * 4u);
        float v0 = zy[a.x & SMASK], v1 = zy[a.y & SMASK];
        float v2 = zy[a.z & SMASK], v3 = zy[a.w & SMASK];
        float v4 = zy[b.x & SMASK], v5 = zy[b.y & SMASK];
        float v6 = zy[b.z & SMASK], v7 = zy[b.w & SMASK];
        atomicAdd(&acc[a.x >> 20], v0);
        atomicAdd(&acc[a.y >> 20], v1);
        atomicAdd(&acc[a.z >> 20], v2);
        atomicAdd(&acc[a.w >> 20], v3);
        atomicAdd(&acc[b.x >> 20], v4);
        atomicAdd(&acc[b.y >> 20], v5);
        atomicAdd(&acc[b.z >> 20], v6);
        atomicAdd(&acc[b.w >> 20], v7);
    }
    for (; g < nv4; g += BT) {
        uint4 a = *(const uint4*)(packed + e0 + (size_t)g * 4u);
        float v0 = zy[a.x & SMASK], v1 = zy[a.y & SMASK];
        float v2 = zy[a.z & SMASK], v3 = zy[a.w & SMASK];
        atomicAdd(&acc[a.x >> 20], v0);
        atomicAdd(&acc[a.y >> 20], v1);
        atomicAdd(&acc[a.z >> 20], v2);
        atomicAdd(&acc[a.w >> 20], v3);
    }
    for (unsigned e = e0 + nv4 * 4u + tid; e < e1; e += BT) {
        unsigned p = packed[e];
        atomicAdd(&acc[p >> 20], zy[p & SMASK]);
    }
    __syncthreads();
    int base = j << BSH;
    for (int t = threadIdx.x; t < BSZ; t += BT) {
        int v = base + t;
        if (v < N)
            out[v] = fmaf(dinv[v], acc[t] + zy[v], b2[0]);
    }
}

// ===================== fallback: global-atomic pipeline ==================

__global__ void f_zero3(float* __restrict__ a, float* __restrict__ b,
                        float* __restrict__ c, int N) {
    int i = blockIdx.x * blockDim.x + threadIdx.x;
    int stride = gridDim.x * blockDim.x;
    for (int v = i; v < N; v += stride) { a[v] = 0.f; b[v] = 0.f; c[v] = 0.f; }
}
__global__ void f_deg(const int* __restrict__ dst, int E, float* __restrict__ degf) {
    int i = blockIdx.x * blockDim.x + threadIdx.x;
    int stride = gridDim.x * blockDim.x;
    for (int e = i; e < E; e += stride) atomicAdd(&degf[dst[e]], 1.0f);
}
__global__ void f_dinv(float* __restrict__ d, int N) {
    int v = blockIdx.x * blockDim.x + threadIdx.x;
    if (v < N) d[v] = rsqrtf(d[v] + 1.0f);
}
__global__ void f_edge1(const int* __restrict__ src, const int* __restrict__ dst,
                        const float* __restrict__ x, const float* __restrict__ dinv,
                        float* __restrict__ acc1, int E) {
    int i = blockIdx.x * blockDim.x + threadIdx.x;
    int stride = gridDim.x * blockDim.x;
    for (int e = i; e < E; e += stride) {
        int s = src[e];
        atomicAdd(&acc1[dst[e]], x[s] * dinv[s]);
    }
}
__global__ void f_node2(const float* __restrict__ dinv, const float* __restrict__ acc1,
                        const float* __restrict__ x, const float* __restrict__ W1,
                        const float* __restrict__ b1, const float* __restrict__ W2,
                        float* __restrict__ zy, int N, int F) {
    int v = blockIdx.x * blockDim.x + threadIdx.x;
    if (v < N) {
        float d = dinv[v];
        float agg = d * (acc1[v] + x[v] * d);
        float z = 0.f;
        for (int f = 0; f < F; ++f) {
            float h = fmaf(W1[f], agg, b1[f]);
            h = h > 0.f ? h : 0.f;
            z = fmaf(h, W2[f], z);
        }
        zy[v] = z * d;
    }
}
__global__ void f_edge2(const int* __restrict__ src, const int* __restrict__ dst,
                        const float* __restrict__ zy, float* __restrict__ out, int E) {
    int i = blockIdx.x * blockDim.x + threadIdx.x;
    int stride = gridDim.x * blockDim.x;
    for (int e = i; e < E; e += stride) atomicAdd(&out[dst[e]], zy[src[e]]);
}
__global__ void f_node3(const float* __restrict__ dinv, const float* __restrict__ zy,
                        const float* __restrict__ b2, float* __restrict__ out, int N) {
    int v = blockIdx.x * blockDim.x + threadIdx.x;
    if (v < N) out[v] = fmaf(dinv[v], out[v] + zy[v], b2[0]);
}

// ===================== launch ===========================================

extern "C" void kernel_launch(void* const* d_in, const int* in_sizes, int n_in,
                              void* d_out, int out_size, void* d_ws, size_t ws_size,
                              hipStream_t stream) {
    const float* x  = (const float*)d_in[0];
    const int*   ei = (const int*)d_in[1];   // harness passes integers as int32
    const float* W1 = (const float*)d_in[2];
    const float* b1 = (const float*)d_in[3];
    const float* W2 = (const float*)d_in[4];
    const float* b2 = (const float*)d_in[5];
    float* out = (float*)d_out;

    const int N = in_sizes[0];
    const int E = in_sizes[1] / 2;
    const int F = in_sizes[2];

    const int* src = ei;
    const int* dst = ei + E;

    const int NB = (N + BSZ - 1) >> BSH;

    // fixed per-bucket capacity: mean + ~12.5% + 1024 slack, multiple of 4.
    unsigned mean = (unsigned)(E / (NB > 0 ? NB : 1));
    unsigned C = (mean + mean / 8u + 1024u + 3u) & ~3u;

    // workspace: [packed NB*C | gcur NBMAX | dinv N | y N | zy N]
    size_t off_packed = 0;
    size_t off_gc     = (off_packed + (size_t)NB * C * 4 + 15) & ~(size_t)15;
    size_t off_dinv   = (off_gc + (size_t)NBMAX * 4 + 15) & ~(size_t)15;
    size_t off_y      = off_dinv + (size_t)N * 4;
    size_t off_zy     = off_y + (size_t)N * 4;
    size_t need       = off_zy + (size_t)N * 4;

    bool ok = (ws_size >= need) && (NB >= 1) && (NB <= NBMAX) &&
              (N <= (1 << 20)) && (F <= 64) && (E > 0);

    char* ws = (char*)d_ws;
    if (ok) {
        unsigned* packed = (unsigned*)(ws + off_packed);
        unsigned* gcur   = (unsigned*)(ws + off_gc);
        float*    dinv   = (float*)(ws + off_dinv);
        float*    y      = (float*)(ws + off_y);
        float*    zy     = (float*)(ws + off_zy);

        int scatBlocks = (E + ST - 1) / ST;

        k_init   <<<1, NBMAX, 0, stream>>>(gcur, C, NB);
        k_scatter<<<scatBlocks, SCT, 0, stream>>>(src, dst, E, gcur, packed, C, NB);
        k_deg    <<<NB, BT, 0, stream>>>(packed, gcur, C, x, dinv, y, N);
        k_acc1   <<<NB, BT, 0, stream>>>(packed, gcur, C, y, dinv, W1, b1, W2, zy, N, F);
        k_out    <<<NB, BT, 0, stream>>>(packed, gcur, C, zy, dinv, b2, out, N);
    } else {
        // fallback: verified global-atomic path (needs 12 MB)
        float* dinv = (float*)(ws);
        float* acc1 = (float*)(ws + (size_t)N * 4);
        float* zy   = (float*)(ws + (size_t)N * 8);
        int nodeBlocks = (N + THREADS - 1) / THREADS;
        int edgeBlocks = (E + THREADS - 1) / THREADS;
        if (edgeBlocks > 2048) edgeBlocks = 2048;
        f_zero3<<<2048, THREADS, 0, stream>>>(dinv, acc1, out, N);
        f_deg  <<<edgeBlocks, THREADS, 0, stream>>>(dst, E, dinv);
        f_dinv <<<nodeBlocks, THREADS, 0, stream>>>(dinv, N);
        f_edge1<<<edgeBlocks, THREADS, 0, stream>>>(src, dst, x, dinv, acc1, E);
        f_node2<<<nodeBlocks, THREADS, 0, stream>>>(dinv, acc1, x, W1, b1, W2, zy, N, F);
        f_edge2<<<edgeBlocks, THREADS, 0, stream>>>(src, dst, zy, out, E);
        f_node3<<<nodeBlocks, THREADS, 0, stream>>>(dinv, zy, b2, out, N);
    }
}

// Round 14
// 122.667 us; speedup vs baseline: 1.2579x; 1.0039x over previous
//
#include <hip/hip_runtime.h>

#define THREADS 256
#define BSH 11          // bucket shift: 2048 nodes per bucket
#define BSZ 2048
#define NBMAX 512
#define ST 8192         // scatter tile size (edges per block)
#define SCT 512         // scatter threads
#define EPT 16          // edges per thread in scatter (ST/SCT)
#define BT 1024         // bucket-kernel threads
#define SMASK 0xFFFFFu  // low 20 bits: src node id

typedef unsigned u32x4_t __attribute__((ext_vector_type(4)));
typedef int      i32x4_t __attribute__((ext_vector_type(4)));

// ===================== binned pipeline =====================

// Init per-bucket allocation cursors: gcur[j] = j*C.
__global__ void k_init(unsigned* __restrict__ gcur, unsigned C, int NB) {
    int t = threadIdx.x;
    if (t < NB) gcur[t] = (unsigned)t * C;
}

// Tile-local counting sort + coalesced write-out into fixed-capacity buckets.
// packed record: src(20b) | dst_local(11b)<<20.  Single LDS atomic per edge
// (rank), shfl-based tile scan (3 barriers), sorted stream-out.
__global__ void __launch_bounds__(SCT)
k_scatter(const int* __restrict__ src,
          const int* __restrict__ dst, int E,
          unsigned* __restrict__ gcur,
          unsigned* __restrict__ packed, unsigned C, int NB) {
    __shared__ unsigned tcnt[NBMAX];
    __shared__ unsigned toff[NBMAX];
    __shared__ unsigned gb[NBMAX];
    __shared__ unsigned wsum[8];
    __shared__ unsigned sorted[ST];
    __shared__ unsigned short jarr[ST];

    int tid = threadIdx.x;
    int lo = blockIdx.x * ST;
    int cnt = E - lo; if (cnt > ST) cnt = ST;   // >0 by grid sizing

    tcnt[tid] = 0u;            // SCT==512==NBMAX
    __syncthreads();

    unsigned jreg[EPT], rreg[EPT], rank[EPT];
    // vectorized nontemporal load: int4 groups of 4 edges (16B aligned)
    #pragma unroll
    for (int kk = 0; kk < EPT / 4; ++kk) {
        int g = kk * SCT + tid;          // group index within tile
        int base = g * 4;
        if (base + 3 < cnt) {
            i32x4_t d4 = __builtin_nontemporal_load((const i32x4_t*)(dst + lo + base));
            i32x4_t s4 = __builtin_nontemporal_load((const i32x4_t*)(src + lo + base));
            unsigned j0 = (unsigned)d4.x >> BSH;
            unsigned j1 = (unsigned)d4.y >> BSH;
            unsigned j2 = (unsigned)d4.z >> BSH;
            unsigned j3 = (unsigned)d4.w >> BSH;
            jreg[kk*4+0] = j0; rreg[kk*4+0] = (unsigned)s4.x | (((unsigned)d4.x & (BSZ-1)) << 20);
            jreg[kk*4+1] = j1; rreg[kk*4+1] = (unsigned)s4.y | (((unsigned)d4.y & (BSZ-1)) << 20);
            jreg[kk*4+2] = j2; rreg[kk*4+2] = (unsigned)s4.z | (((unsigned)d4.z & (BSZ-1)) << 20);
            jreg[kk*4+3] = j3; rreg[kk*4+3] = (unsigned)s4.w | (((unsigned)d4.w & (BSZ-1)) << 20);
            rank[kk*4+0] = atomicAdd(&tcnt[j0], 1u);
            rank[kk*4+1] = atomicAdd(&tcnt[j1], 1u);
            rank[kk*4+2] = atomicAdd(&tcnt[j2], 1u);
            rank[kk*4+3] = atomicAdd(&tcnt[j3], 1u);
        } else {
            #pragma unroll
            for (int c = 0; c < 4; ++c) {
                int idx = base + c;
                if (idx < cnt) {
                    int d = dst[lo + idx];
                    unsigned jj = (unsigned)d >> BSH;
                    jreg[kk*4+c] = jj;
                    rreg[kk*4+c] = (unsigned)src[lo + idx] | (((unsigned)d & (BSZ-1)) << 20);
                    rank[kk*4+c] = atomicAdd(&tcnt[jj], 1u);
                } else {
                    jreg[kk*4+c] = ~0u;
                }
            }
        }
    }
    __syncthreads();

    // 2-level shfl scan of tcnt[0..512) -> exclusive toff; reserve runs
    {
        unsigned v = tcnt[tid];
        unsigned incl = v;
        #pragma unroll
        for (int off = 1; off < 64; off <<= 1) {
            unsigned u = __shfl_up(incl, off, 64);
            if ((tid & 63) >= off) incl += u;
        }
        unsigned wid = tid >> 6;             // 8 waves
        if ((tid & 63) == 63) wsum[wid] = incl;
        __syncthreads();
        if (tid < 8) {
            unsigned wi = wsum[tid];
            #pragma unroll
            for (int off = 1; off < 8; off <<= 1) {
                unsigned u = __shfl_up(wi, off, 8);
                if (tid >= off) wi += u;
            }
            wsum[tid] = wi;                  // inclusive over waves
        }
        __syncthreads();
        unsigned wbase = wid ? wsum[wid - 1] : 0u;
        unsigned excl = wbase + incl - v;
        toff[tid] = excl;
        if (v) gb[tid] = atomicAdd(&gcur[tid], v);
    }
    __syncthreads();

    // place records into tile-sorted LDS order (slot = toff + rank)
    #pragma unroll
    for (int k = 0; k < EPT; ++k) {
        unsigned jj = jreg[k];
        if (jj != ~0u) {
            unsigned p = toff[jj] + rank[k];
            sorted[p] = rreg[k];
            jarr[p] = (unsigned short)jj;
        }
    }
    __syncthreads();

    // stream out: consecutive p -> consecutive global dest within each run
    for (int p = tid; p < cnt; p += SCT) {
        unsigned jj = jarr[p];
        unsigned pos = gb[jj] + ((unsigned)p - toff[jj]);
        if (pos < (jj + 1u) * C)
            __builtin_nontemporal_store(sorted[p], &packed[pos]);
    }
}

// Per-bucket degree count in LDS -> dinv & y = x*dinv (exclusive node range).
__global__ void k_deg(const unsigned* __restrict__ packed,
                      const unsigned* __restrict__ gcur, unsigned C,
                      const float* __restrict__ x,
                      float* __restrict__ dinv, float* __restrict__ y, int N) {
    int j = blockIdx.x;
    __shared__ unsigned cntl[BSZ];
    for (int t = threadIdx.x; t < BSZ; t += BT) cntl[t] = 0u;
    __syncthreads();
    unsigned e0 = (unsigned)j * C;                    // C%4==0 -> 16B aligned
    unsigned e1 = gcur[j]; if (e1 > e0 + C) e1 = e0 + C;
    unsigned tid = threadIdx.x;
    unsigned nv4 = (e1 - e0) >> 2;
    unsigned g = tid;
    for (; g + BT < nv4; g += 2u * BT) {
        u32x4_t a = __builtin_nontemporal_load((const u32x4_t*)(packed + e0 + (size_t)g * 4u));
        u32x4_t b = __builtin_nontemporal_load((const u32x4_t*)(packed + e0 + (size_t)(g + BT) * 4u));
        atomicAdd(&cntl[a.x >> 20], 1u);
        atomicAdd(&cntl[a.y >> 20], 1u);
        atomicAdd(&cntl[a.z >> 20], 1u);
        atomicAdd(&cntl[a.w >> 20], 1u);
        atomicAdd(&cntl[b.x >> 20], 1u);
        atomicAdd(&cntl[b.y >> 20], 1u);
        atomicAdd(&cntl[b.z >> 20], 1u);
        atomicAdd(&cntl[b.w >> 20], 1u);
    }
    for (; g < nv4; g += BT) {
        u32x4_t a = __builtin_nontemporal_load((const u32x4_t*)(packed + e0 + (size_t)g * 4u));
        atomicAdd(&cntl[a.x >> 20], 1u);
        atomicAdd(&cntl[a.y >> 20], 1u);
        atomicAdd(&cntl[a.z >> 20], 1u);
        atomicAdd(&cntl[a.w >> 20], 1u);
    }
    for (unsigned e = e0 + nv4 * 4u + tid; e < e1; e += BT)
        atomicAdd(&cntl[packed[e] >> 20], 1u);
    __syncthreads();
    int base = j << BSH;
    for (int t = threadIdx.x; t < BSZ; t += BT) {
        int v = base + t;
        if (v < N) {
            float d = rsqrtf((float)cntl[t] + 1.0f);
            dinv[v] = d;
            y[v] = x[v] * d;
        }
    }
}

// Layer-1 aggregate (LDS) + fused per-node MLP -> zy = z*dinv.
__global__ void k_acc1(const unsigned* __restrict__ packed,
                       const unsigned* __restrict__ gcur, unsigned C,
                       const float* __restrict__ y,
                       const float* __restrict__ dinv,
                       const float* __restrict__ W1,
                       const float* __restrict__ b1,
                       const float* __restrict__ W2,
                       float* __restrict__ zy, int N, int F) {
    int j = blockIdx.x;
    __shared__ float acc[BSZ];
    __shared__ float w1s[64], b1s[64], w2s[64];
    for (int t = threadIdx.x; t < BSZ; t += BT) acc[t] = 0.f;
    if (threadIdx.x < (unsigned)F) {
        w1s[threadIdx.x] = W1[threadIdx.x];
        b1s[threadIdx.x] = b1[threadIdx.x];
        w2s[threadIdx.x] = W2[threadIdx.x];
    }
    __syncthreads();
    unsigned e0 = (unsigned)j * C;
    unsigned e1 = gcur[j]; if (e1 > e0 + C) e1 = e0 + C;
    unsigned tid = threadIdx.x;
    unsigned nv4 = (e1 - e0) >> 2;
    unsigned g = tid;
    for (; g + BT < nv4; g += 2u * BT) {
        u32x4_t a = __builtin_nontemporal_load((const u32x4_t*)(packed + e0 + (size_t)g * 4u));
        u32x4_t b = __builtin_nontemporal_load((const u32x4_t*)(packed + e0 + (size_t)(g + BT) * 4u));
        float v0 = y[a.x & SMASK], v1 = y[a.y & SMASK];
        float v2 = y[a.z & SMASK], v3 = y[a.w & SMASK];
        float v4 = y[b.x & SMASK], v5 = y[b.y & SMASK];
        float v6 = y[b.z & SMASK], v7 = y[b.w & SMASK];
        atomicAdd(&acc[a.x >> 20], v0);
        atomicAdd(&acc[a.y >> 20], v1);
        atomicAdd(&acc[a.z >> 20], v2);
        atomicAdd(&acc[a.w >> 20], v3);
        atomicAdd(&acc[b.x >> 20], v4);
        atomicAdd(&acc[b.y >> 20], v5);
        atomicAdd(&acc[b.z >> 20], v6);
        atomicAdd(&acc[b.w >> 20], v7);
    }
    for (; g < nv4; g += BT) {
        u32x4_t a = __builtin_nontemporal_load((const u32x4_t*)(packed + e0 + (size_t)g * 4u));
        float v0 = y[a.x & SMASK], v1 = y[a.y & SMASK];
        float v2 = y[a.z & SMASK], v3 = y[a.w & SMASK];
        atomicAdd(&acc[a.x >> 20], v0);
        atomicAdd(&acc[a.y >> 20], v1);
        atomicAdd(&acc[a.z >> 20], v2);
        atomicAdd(&acc[a.w >> 20], v3);
    }
    for (unsigned e = e0 + nv4 * 4u + tid; e < e1; e += BT) {
        unsigned p = packed[e];
        atomicAdd(&acc[p >> 20], y[p & SMASK]);
    }
    __syncthreads();
    int base = j << BSH;
    for (int t = threadIdx.x; t < BSZ; t += BT) {
        int v = base + t;
        if (v < N) {
            float d = dinv[v];
            float agg = d * (acc[t] + y[v]);
            float z = 0.f;
            for (int f = 0; f < F; ++f) {
                float h = fmaf(w1s[f], agg, b1s[f]);
                h = fmaxf(h, 0.f);
                z = fmaf(h, w2s[f], z);
            }
            zy[v] = z * d;
        }
    }
}

// Layer-2 aggregate (LDS) -> out = dinv*(acc + zy) + b2.
__global__ void k_out(const unsigned* __restrict__ packed,
                      const unsigned* __restrict__ gcur, unsigned C,
                      const float* __restrict__ zy,
                      const float* __restrict__ dinv,
                      const float* __restrict__ b2,
                      float* __restrict__ out, int N) {
    int j = blockIdx.x;
    __shared__ float acc[BSZ];
    for (int t = threadIdx.x; t < BSZ; t += BT) acc[t] = 0.f;
    __syncthreads();
    unsigned e0 = (unsigned)j * C;
    unsigned e1 = gcur[j]; if (e1 > e0 + C) e1 = e0 + C;
    unsigned tid = threadIdx.x;
    unsigned nv4 = (e1 - e0) >> 2;
    unsigned g = tid;
    for (; g + BT < nv4; g += 2u * BT) {
        u32x4_t a = __builtin_nontemporal_load((const u32x4_t*)(packed + e0 + (size_t)g * 4u));
        u32x4_t b = __builtin_nontemporal_load((const u32x4_t*)(packed + e0 + (size_t)(g + BT) * 4u));
        float v0 = zy[a.x & SMASK], v1 = zy[a.y & SMASK];
        float v2 = zy[a.z & SMASK], v3 = zy[a.w & SMASK];
        float v4 = zy[b.x & SMASK], v5 = zy[b.y & SMASK];
        float v6 = zy[b.z & SMASK], v7 = zy[b.w & SMASK];
        atomicAdd(&acc[a.x >> 20], v0);
        atomicAdd(&acc[a.y >> 20], v1);
        atomicAdd(&acc[a.z >> 20], v2);
        atomicAdd(&acc[a.w >> 20], v3);
        atomicAdd(&acc[b.x >> 20], v4);
        atomicAdd(&acc[b.y >> 20], v5);
        atomicAdd(&acc[b.z >> 20], v6);
        atomicAdd(&acc[b.w >> 20], v7);
    }
    for (; g < nv4; g += BT) {
        u32x4_t a = __builtin_nontemporal_load((const u32x4_t*)(packed + e0 + (size_t)g * 4u));
        float v0 = zy[a.x & SMASK], v1 = zy[a.y & SMASK];
        float v2 = zy[a.z & SMASK], v3 = zy[a.w & SMASK];
        atomicAdd(&acc[a.x >> 20], v0);
        atomicAdd(&acc[a.y >> 20], v1);
        atomicAdd(&acc[a.z >> 20], v2);
        atomicAdd(&acc[a.w >> 20], v3);
    }
    for (unsigned e = e0 + nv4 * 4u + tid; e < e1; e += BT) {
        unsigned p = packed[e];
        atomicAdd(&acc[p >> 20], zy[p & SMASK]);
    }
    __syncthreads();
    int base = j << BSH;
    for (int t = threadIdx.x; t < BSZ; t += BT) {
        int v = base + t;
        if (v < N)
            out[v] = fmaf(dinv[v], acc[t] + zy[v], b2[0]);
    }
}

// ===================== fallback: global-atomic pipeline ==================

__global__ void f_zero3(float* __restrict__ a, float* __restrict__ b,
                        float* __restrict__ c, int N) {
    int i = blockIdx.x * blockDim.x + threadIdx.x;
    int stride = gridDim.x * blockDim.x;
    for (int v = i; v < N; v += stride) { a[v] = 0.f; b[v] = 0.f; c[v] = 0.f; }
}
__global__ void f_deg(const int* __restrict__ dst, int E, float* __restrict__ degf) {
    int i = blockIdx.x * blockDim.x + threadIdx.x;
    int stride = gridDim.x * blockDim.x;
    for (int e = i; e < E; e += stride) atomicAdd(&degf[dst[e]], 1.0f);
}
__global__ void f_dinv(float* __restrict__ d, int N) {
    int v = blockIdx.x * blockDim.x + threadIdx.x;
    if (v < N) d[v] = rsqrtf(d[v] + 1.0f);
}
__global__ void f_edge1(const int* __restrict__ src, const int* __restrict__ dst,
                        const float* __restrict__ x, const float* __restrict__ dinv,
                        float* __restrict__ acc1, int E) {
    int i = blockIdx.x * blockDim.x + threadIdx.x;
    int stride = gridDim.x * blockDim.x;
    for (int e = i; e < E; e += stride) {
        int s = src[e];
        atomicAdd(&acc1[dst[e]], x[s] * dinv[s]);
    }
}
__global__ void f_node2(const float* __restrict__ dinv, const float* __restrict__ acc1,
                        const float* __restrict__ x, const float* __restrict__ W1,
                        const float* __restrict__ b1, const float* __restrict__ W2,
                        float* __restrict__ zy, int N, int F) {
    int v = blockIdx.x * blockDim.x + threadIdx.x;
    if (v < N) {
        float d = dinv[v];
        float agg = d * (acc1[v] + x[v] * d);
        float z = 0.f;
        for (int f = 0; f < F; ++f) {
            float h = fmaf(W1[f], agg, b1[f]);
            h = h > 0.f ? h : 0.f;
            z = fmaf(h, W2[f], z);
        }
        zy[v] = z * d;
    }
}
__global__ void f_edge2(const int* __restrict__ src, const int* __restrict__ dst,
                        const float* __restrict__ zy, float* __restrict__ out, int E) {
    int i = blockIdx.x * blockDim.x + threadIdx.x;
    int stride = gridDim.x * blockDim.x;
    for (int e = i; e < E; e += stride) atomicAdd(&out[dst[e]], zy[src[e]]);
}
__global__ void f_node3(const float* __restrict__ dinv, const float* __restrict__ zy,
                        const float* __restrict__ b2, float* __restrict__ out, int N) {
    int v = blockIdx.x * blockDim.x + threadIdx.x;
    if (v < N) out[v] = fmaf(dinv[v], out[v] + zy[v], b2[0]);
}

// ===================== launch ===========================================

extern "C" void kernel_launch(void* const* d_in, const int* in_sizes, int n_in,
                              void* d_out, int out_size, void* d_ws, size_t ws_size,
                              hipStream_t stream) {
    const float* x  = (const float*)d_in[0];
    const int*   ei = (const int*)d_in[1];   // harness passes integers as int32
    const float* W1 = (const float*)d_in[2];
    const float* b1 = (const float*)d_in[3];
    const float* W2 = (const float*)d_in[4];
    const float* b2 = (const float*)d_in[5];
    float* out = (float*)d_out;

    const int N = in_sizes[0];
    const int E = in_sizes[1] / 2;
    const int F = in_sizes[2];

    const int* src = ei;
    const int* dst = ei + E;

    const int NB = (N + BSZ - 1) >> BSH;

    // fixed per-bucket capacity: mean + ~12.5% + 1024 slack, multiple of 4.
    unsigned mean = (unsigned)(E / (NB > 0 ? NB : 1));
    unsigned C = (mean + mean / 8u + 1024u + 3u) & ~3u;

    // workspace: [packed NB*C | gcur NBMAX | dinv N | y N | zy N]
    size_t off_packed = 0;
    size_t off_gc     = (off_packed + (size_t)NB * C * 4 + 15) & ~(size_t)15;
    size_t off_dinv   = (off_gc + (size_t)NBMAX * 4 + 15) & ~(size_t)15;
    size_t off_y      = off_dinv + (size_t)N * 4;
    size_t off_zy     = off_y + (size_t)N * 4;
    size_t need       = off_zy + (size_t)N * 4;

    bool ok = (ws_size >= need) && (NB >= 1) && (NB <= NBMAX) &&
              (N <= (1 << 20)) && (F <= 64) && (E > 0);

    char* ws = (char*)d_ws;
    if (ok) {
        unsigned* packed = (unsigned*)(ws + off_packed);
        unsigned* gcur   = (unsigned*)(ws + off_gc);
        float*    dinv   = (float*)(ws + off_dinv);
        float*    y      = (float*)(ws + off_y);
        float*    zy     = (float*)(ws + off_zy);

        int scatBlocks = (E + ST - 1) / ST;

        k_init   <<<1, NBMAX, 0, stream>>>(gcur, C, NB);
        k_scatter<<<scatBlocks, SCT, 0, stream>>>(src, dst, E, gcur, packed, C, NB);
        k_deg    <<<NB, BT, 0, stream>>>(packed, gcur, C, x, dinv, y, N);
        k_acc1   <<<NB, BT, 0, stream>>>(packed, gcur, C, y, dinv, W1, b1, W2, zy, N, F);
        k_out    <<<NB, BT, 0, stream>>>(packed, gcur, C, zy, dinv, b2, out, N);
    } else {
        // fallback: verified global-atomic path (needs 12 MB)
        float* dinv = (float*)(ws);
        float* acc1 = (float*)(ws + (size_t)N * 4);
        float* zy   = (float*)(ws + (size_t)N * 8);
        int nodeBlocks = (N + THREADS - 1) / THREADS;
        int edgeBlocks = (E + THREADS - 1) / THREADS;
        if (edgeBlocks > 2048) edgeBlocks = 2048;
        f_zero3<<<2048, THREADS, 0, stream>>>(dinv, acc1, out, N);
        f_deg  <<<edgeBlocks, THREADS, 0, stream>>>(dst, E, dinv);
        f_dinv <<<nodeBlocks, THREADS, 0, stream>>>(dinv, N);
        f_edge1<<<edgeBlocks, THREADS, 0, stream>>>(src, dst, x, dinv, acc1, E);
        f_node2<<<nodeBlocks, THREADS, 0, stream>>>(dinv, acc1, x, W1, b1, W2, zy, N, F);
        f_edge2<<<edgeBlocks, THREADS, 0, stream>>>(src, dst, zy, out, E);
        f_node3<<<nodeBlocks, THREADS, 0, stream>>>(dinv, zy, b2, out, N);
    }
}

// Round 15
// 111.030 us; speedup vs baseline: 1.3897x; 1.1048x over previous
//
#include <hip/hip_runtime.h>

#define THREADS 256
#define BSH 11          // bucket shift: 2048 nodes per bucket
#define BSZ 2048
#define NBMAX 512
#define ST 8192         // scatter tile size (edges per block)
#define SCT 512         // scatter threads
#define EPT 16          // edges per thread in scatter (ST/SCT)
#define BT 1024         // bucket-kernel threads
#define SMASK 0xFFFFFu  // low 20 bits: src node id

typedef unsigned u32x4_t __attribute__((ext_vector_type(4)));

// ===================== binned pipeline =====================

// Init per-bucket allocation cursors: gcur[j] = j*C.
__global__ void k_init(unsigned* __restrict__ gcur, unsigned C, int NB) {
    int t = threadIdx.x;
    if (t < NB) gcur[t] = (unsigned)t * C;
}

// Tile-local counting sort + coalesced write-out into fixed-capacity buckets.
// packed record: src(20b) | dst_local(11b)<<20.  (verified r10: 109.3 us)
__global__ void __launch_bounds__(SCT)
k_scatter(const int* __restrict__ src,
          const int* __restrict__ dst, int E,
          unsigned* __restrict__ gcur,
          unsigned* __restrict__ packed, unsigned C, int NB) {
    __shared__ unsigned tcnt[NBMAX];
    __shared__ unsigned toff[NBMAX];
    __shared__ unsigned gb[NBMAX];
    __shared__ unsigned sh[NBMAX];
    __shared__ unsigned sorted[ST];
    __shared__ unsigned short jarr[ST];

    int tid = threadIdx.x;
    int lo = blockIdx.x * ST;
    int cnt = E - lo; if (cnt > ST) cnt = ST;   // >0 by grid sizing

    tcnt[tid] = 0u;            // SCT==512==NBMAX
    __syncthreads();

    unsigned jreg[EPT], rreg[EPT], rank[EPT];
    // vectorized load: int4 groups of 4 consecutive edges (lo is 16B-aligned)
    #pragma unroll
    for (int kk = 0; kk < EPT / 4; ++kk) {
        int g = kk * SCT + tid;          // group index within tile
        int base = g * 4;
        if (base + 3 < cnt) {
            int4 d4 = *(const int4*)(dst + lo + base);
            int4 s4 = *(const int4*)(src + lo + base);
            unsigned j0 = (unsigned)d4.x >> BSH;
            unsigned j1 = (unsigned)d4.y >> BSH;
            unsigned j2 = (unsigned)d4.z >> BSH;
            unsigned j3 = (unsigned)d4.w >> BSH;
            jreg[kk*4+0] = j0; rreg[kk*4+0] = (unsigned)s4.x | (((unsigned)d4.x & (BSZ-1)) << 20);
            jreg[kk*4+1] = j1; rreg[kk*4+1] = (unsigned)s4.y | (((unsigned)d4.y & (BSZ-1)) << 20);
            jreg[kk*4+2] = j2; rreg[kk*4+2] = (unsigned)s4.z | (((unsigned)d4.z & (BSZ-1)) << 20);
            jreg[kk*4+3] = j3; rreg[kk*4+3] = (unsigned)s4.w | (((unsigned)d4.w & (BSZ-1)) << 20);
            rank[kk*4+0] = atomicAdd(&tcnt[j0], 1u);
            rank[kk*4+1] = atomicAdd(&tcnt[j1], 1u);
            rank[kk*4+2] = atomicAdd(&tcnt[j2], 1u);
            rank[kk*4+3] = atomicAdd(&tcnt[j3], 1u);
        } else {
            #pragma unroll
            for (int c = 0; c < 4; ++c) {
                int idx = base + c;
                if (idx < cnt) {
                    int d = dst[lo + idx];
                    unsigned jj = (unsigned)d >> BSH;
                    jreg[kk*4+c] = jj;
                    rreg[kk*4+c] = (unsigned)src[lo + idx] | (((unsigned)d & (BSZ-1)) << 20);
                    rank[kk*4+c] = atomicAdd(&tcnt[jj], 1u);
                } else {
                    jreg[kk*4+c] = ~0u;
                }
            }
        }
    }
    __syncthreads();

    // scan tile histogram (512 wide, SCT=512 threads); reserve global space
    unsigned v = tcnt[tid];
    sh[tid] = v;
    __syncthreads();
    for (int off = 1; off < NBMAX; off <<= 1) {
        unsigned t = (tid >= off) ? sh[tid - off] : 0u;
        __syncthreads();
        sh[tid] += t;
        __syncthreads();
    }
    {
        unsigned excl = sh[tid] - v;
        toff[tid] = excl;
        if (v) gb[tid] = atomicAdd(&gcur[tid], v);
    }
    __syncthreads();

    // place records into tile-sorted LDS order (slot = toff + rank)
    #pragma unroll
    for (int k = 0; k < EPT; ++k) {
        unsigned jj = jreg[k];
        if (jj != ~0u) {
            unsigned p = toff[jj] + rank[k];
            sorted[p] = rreg[k];
            jarr[p] = (unsigned short)jj;
        }
    }
    __syncthreads();

    // stream out: consecutive p -> consecutive global dest within each run.
    for (int p = tid; p < cnt; p += SCT) {
        unsigned jj = jarr[p];
        unsigned pos = gb[jj] + ((unsigned)p - toff[jj]);
        if (pos < (jj + 1u) * C) packed[pos] = sorted[p];
    }
}

// Per-bucket degree count in LDS -> dinv & y = x*dinv (exclusive node range).
__global__ void k_deg(const unsigned* __restrict__ packed,
                      const unsigned* __restrict__ gcur, unsigned C,
                      const float* __restrict__ x,
                      float* __restrict__ dinv, float* __restrict__ y, int N) {
    int j = blockIdx.x;
    __shared__ unsigned cntl[BSZ];
    for (int t = threadIdx.x; t < BSZ; t += BT) cntl[t] = 0u;
    __syncthreads();
    unsigned e0 = (unsigned)j * C;                    // C%4==0 -> 16B aligned
    unsigned e1 = gcur[j]; if (e1 > e0 + C) e1 = e0 + C;
    unsigned tid = threadIdx.x;
    unsigned nv4 = (e1 - e0) >> 2;
    unsigned g = tid;
    for (; g + BT < nv4; g += 2u * BT) {
        uint4 a = *(const uint4*)(packed + e0 + (size_t)g * 4u);
        uint4 b = *(const uint4*)(packed + e0 + (size_t)(g + BT) * 4u);
        atomicAdd(&cntl[a.x >> 20], 1u);
        atomicAdd(&cntl[a.y >> 20], 1u);
        atomicAdd(&cntl[a.z >> 20], 1u);
        atomicAdd(&cntl[a.w >> 20], 1u);
        atomicAdd(&cntl[b.x >> 20], 1u);
        atomicAdd(&cntl[b.y >> 20], 1u);
        atomicAdd(&cntl[b.z >> 20], 1u);
        atomicAdd(&cntl[b.w >> 20], 1u);
    }
    for (; g < nv4; g += BT) {
        uint4 a = *(const uint4*)(packed + e0 + (size_t)g * 4u);
        atomicAdd(&cntl[a.x >> 20], 1u);
        atomicAdd(&cntl[a.y >> 20], 1u);
        atomicAdd(&cntl[a.z >> 20], 1u);
        atomicAdd(&cntl[a.w >> 20], 1u);
    }
    for (unsigned e = e0 + nv4 * 4u + tid; e < e1; e += BT)
        atomicAdd(&cntl[packed[e] >> 20], 1u);
    __syncthreads();
    int base = j << BSH;
    for (int t = threadIdx.x; t < BSZ; t += BT) {
        int v = base + t;
        if (v < N) {
            float d = rsqrtf((float)cntl[t] + 1.0f);
            dinv[v] = d;
            y[v] = x[v] * d;
        }
    }
}

// Layer-1 aggregate (LDS) + fused per-node MLP -> zy = z*dinv.
// packed reads are NON-TEMPORAL: evict-first so the 4MB y table stays in L2.
__global__ void k_acc1(const unsigned* __restrict__ packed,
                       const unsigned* __restrict__ gcur, unsigned C,
                       const float* __restrict__ y,
                       const float* __restrict__ dinv,
                       const float* __restrict__ W1,
                       const float* __restrict__ b1,
                       const float* __restrict__ W2,
                       float* __restrict__ zy, int N, int F) {
    int j = blockIdx.x;
    __shared__ float acc[BSZ];
    __shared__ float w1s[64], b1s[64], w2s[64];
    for (int t = threadIdx.x; t < BSZ; t += BT) acc[t] = 0.f;
    if (threadIdx.x < (unsigned)F) {
        w1s[threadIdx.x] = W1[threadIdx.x];
        b1s[threadIdx.x] = b1[threadIdx.x];
        w2s[threadIdx.x] = W2[threadIdx.x];
    }
    __syncthreads();
    unsigned e0 = (unsigned)j * C;
    unsigned e1 = gcur[j]; if (e1 > e0 + C) e1 = e0 + C;
    unsigned tid = threadIdx.x;
    unsigned nv4 = (e1 - e0) >> 2;
    unsigned g = tid;
    for (; g + BT < nv4; g += 2u * BT) {
        u32x4_t a = __builtin_nontemporal_load((const u32x4_t*)(packed + e0 + (size_t)g * 4u));
        u32x4_t b = __builtin_nontemporal_load((const u32x4_t*)(packed + e0 + (size_t)(g + BT) * 4u));
        float v0 = y[a.x & SMASK], v1 = y[a.y & SMASK];
        float v2 = y[a.z & SMASK], v3 = y[a.w & SMASK];
        float v4 = y[b.x & SMASK], v5 = y[b.y & SMASK];
        float v6 = y[b.z & SMASK], v7 = y[b.w & SMASK];
        atomicAdd(&acc[a.x >> 20], v0);
        atomicAdd(&acc[a.y >> 20], v1);
        atomicAdd(&acc[a.z >> 20], v2);
        atomicAdd(&acc[a.w >> 20], v3);
        atomicAdd(&acc[b.x >> 20], v4);
        atomicAdd(&acc[b.y >> 20], v5);
        atomicAdd(&acc[b.z >> 20], v6);
        atomicAdd(&acc[b.w >> 20], v7);
    }
    for (; g < nv4; g += BT) {
        u32x4_t a = __builtin_nontemporal_load((const u32x4_t*)(packed + e0 + (size_t)g * 4u));
        float v0 = y[a.x & SMASK], v1 = y[a.y & SMASK];
        float v2 = y[a.z & SMASK], v3 = y[a.w & SMASK];
        atomicAdd(&acc[a.x >> 20], v0);
        atomicAdd(&acc[a.y >> 20], v1);
        atomicAdd(&acc[a.z >> 20], v2);
        atomicAdd(&acc[a.w >> 20], v3);
    }
    for (unsigned e = e0 + nv4 * 4u + tid; e < e1; e += BT) {
        unsigned p = packed[e];
        atomicAdd(&acc[p >> 20], y[p & SMASK]);
    }
    __syncthreads();
    int base = j << BSH;
    for (int t = threadIdx.x; t < BSZ; t += BT) {
        int v = base + t;
        if (v < N) {
            float d = dinv[v];
            float agg = d * (acc[t] + y[v]);
            float z = 0.f;
            for (int f = 0; f < F; ++f) {
                float h = fmaf(w1s[f], agg, b1s[f]);
                h = fmaxf(h, 0.f);
                z = fmaf(h, w2s[f], z);
            }
            zy[v] = z * d;
        }
    }
}

// Layer-2 aggregate (LDS) -> out = dinv*(acc + zy) + b2.  NT packed reads.
__global__ void k_out(const unsigned* __restrict__ packed,
                      const unsigned* __restrict__ gcur, unsigned C,
                      const float* __restrict__ zy,
                      const float* __restrict__ dinv,
                      const float* __restrict__ b2,
                      float* __restrict__ out, int N) {
    int j = blockIdx.x;
    __shared__ float acc[BSZ];
    for (int t = threadIdx.x; t < BSZ; t += BT) acc[t] = 0.f;
    __syncthreads();
    unsigned e0 = (unsigned)j * C;
    unsigned e1 = gcur[j]; if (e1 > e0 + C) e1 = e0 + C;
    unsigned tid = threadIdx.x;
    unsigned nv4 = (e1 - e0) >> 2;
    unsigned g = tid;
    for (; g + BT < nv4; g += 2u * BT) {
        u32x4_t a = __builtin_nontemporal_load((const u32x4_t*)(packed + e0 + (size_t)g * 4u));
        u32x4_t b = __builtin_nontemporal_load((const u32x4_t*)(packed + e0 + (size_t)(g + BT) * 4u));
        float v0 = zy[a.x & SMASK], v1 = zy[a.y & SMASK];
        float v2 = zy[a.z & SMASK], v3 = zy[a.w & SMASK];
        float v4 = zy[b.x & SMASK], v5 = zy[b.y & SMASK];
        float v6 = zy[b.z & SMASK], v7 = zy[b.w & SMASK];
        atomicAdd(&acc[a.x >> 20], v0);
        atomicAdd(&acc[a.y >> 20], v1);
        atomicAdd(&acc[a.z >> 20], v2);
        atomicAdd(&acc[a.w >> 20], v3);
        atomicAdd(&acc[b.x >> 20], v4);
        atomicAdd(&acc[b.y >> 20], v5);
        atomicAdd(&acc[b.z >> 20], v6);
        atomicAdd(&acc[b.w >> 20], v7);
    }
    for (; g < nv4; g += BT) {
        u32x4_t a = __builtin_nontemporal_load((const u32x4_t*)(packed + e0 + (size_t)g * 4u));
        float v0 = zy[a.x & SMASK], v1 = zy[a.y & SMASK];
        float v2 = zy[a.z & SMASK], v3 = zy[a.w & SMASK];
        atomicAdd(&acc[a.x >> 20], v0);
        atomicAdd(&acc[a.y >> 20], v1);
        atomicAdd(&acc[a.z >> 20], v2);
        atomicAdd(&acc[a.w >> 20], v3);
    }
    for (unsigned e = e0 + nv4 * 4u + tid; e < e1; e += BT) {
        unsigned p = packed[e];
        atomicAdd(&acc[p >> 20], zy[p & SMASK]);
    }
    __syncthreads();
    int base = j << BSH;
    for (int t = threadIdx.x; t < BSZ; t += BT) {
        int v = base + t;
        if (v < N)
            out[v] = fmaf(dinv[v], acc[t] + zy[v], b2[0]);
    }
}

// ===================== fallback: global-atomic pipeline ==================

__global__ void f_zero3(float* __restrict__ a, float* __restrict__ b,
                        float* __restrict__ c, int N) {
    int i = blockIdx.x * blockDim.x + threadIdx.x;
    int stride = gridDim.x * blockDim.x;
    for (int v = i; v < N; v += stride) { a[v] = 0.f; b[v] = 0.f; c[v] = 0.f; }
}
__global__ void f_deg(const int* __restrict__ dst, int E, float* __restrict__ degf) {
    int i = blockIdx.x * blockDim.x + threadIdx.x;
    int stride = gridDim.x * blockDim.x;
    for (int e = i; e < E; e += stride) atomicAdd(&degf[dst[e]], 1.0f);
}
__global__ void f_dinv(float* __restrict__ d, int N) {
    int v = blockIdx.x * blockDim.x + threadIdx.x;
    if (v < N) d[v] = rsqrtf(d[v] + 1.0f);
}
__global__ void f_edge1(const int* __restrict__ src, const int* __restrict__ dst,
                        const float* __restrict__ x, const float* __restrict__ dinv,
                        float* __restrict__ acc1, int E) {
    int i = blockIdx.x * blockDim.x + threadIdx.x;
    int stride = gridDim.x * blockDim.x;
    for (int e = i; e < E; e += stride) {
        int s = src[e];
        atomicAdd(&acc1[dst[e]], x[s] * dinv[s]);
    }
}
__global__ void f_node2(const float* __restrict__ dinv, const float* __restrict__ acc1,
                        const float* __restrict__ x, const float* __restrict__ W1,
                        const float* __restrict__ b1, const float* __restrict__ W2,
                        float* __restrict__ zy, int N, int F) {
    int v = blockIdx.x * blockDim.x + threadIdx.x;
    if (v < N) {
        float d = dinv[v];
        float agg = d * (acc1[v] + x[v] * d);
        float z = 0.f;
        for (int f = 0; f < F; ++f) {
            float h = fmaf(W1[f], agg, b1[f]);
            h = h > 0.f ? h : 0.f;
            z = fmaf(h, W2[f], z);
        }
        zy[v] = z * d;
    }
}
__global__ void f_edge2(const int* __restrict__ src, const int* __restrict__ dst,
                        const float* __restrict__ zy, float* __restrict__ out, int E) {
    int i = blockIdx.x * blockDim.x + threadIdx.x;
    int stride = gridDim.x * blockDim.x;
    for (int e = i; e < E; e += stride) atomicAdd(&out[dst[e]], zy[src[e]]);
}
__global__ void f_node3(const float* __restrict__ dinv, const float* __restrict__ zy,
                        const float* __restrict__ b2, float* __restrict__ out, int N) {
    int v = blockIdx.x * blockDim.x + threadIdx.x;
    if (v < N) out[v] = fmaf(dinv[v], out[v] + zy[v], b2[0]);
}

// ===================== launch ===========================================

extern "C" void kernel_launch(void* const* d_in, const int* in_sizes, int n_in,
                              void* d_out, int out_size, void* d_ws, size_t ws_size,
                              hipStream_t stream) {
    const float* x  = (const float*)d_in[0];
    const int*   ei = (const int*)d_in[1];   // harness passes integers as int32
    const float* W1 = (const float*)d_in[2];
    const float* b1 = (const float*)d_in[3];
    const float* W2 = (const float*)d_in[4];
    const float* b2 = (const float*)d_in[5];
    float* out = (float*)d_out;

    const int N = in_sizes[0];
    const int E = in_sizes[1] / 2;
    const int F = in_sizes[2];

    const int* src = ei;
    const int* dst = ei + E;

    const int NB = (N + BSZ - 1) >> BSH;

    // fixed per-bucket capacity: mean + ~12.5% + 1024 slack, multiple of 4.
    unsigned mean = (unsigned)(E / (NB > 0 ? NB : 1));
    unsigned C = (mean + mean / 8u + 1024u + 3u) & ~3u;

    // workspace: [packed NB*C | gcur NBMAX | dinv N | y N | zy N]
    size_t off_packed = 0;
    size_t off_gc     = (off_packed + (size_t)NB * C * 4 + 15) & ~(size_t)15;
    size_t off_dinv   = (off_gc + (size_t)NBMAX * 4 + 15) & ~(size_t)15;
    size_t off_y      = off_dinv + (size_t)N * 4;
    size_t off_zy     = off_y + (size_t)N * 4;
    size_t need       = off_zy + (size_t)N * 4;

    bool ok = (ws_size >= need) && (NB >= 1) && (NB <= NBMAX) &&
              (N <= (1 << 20)) && (F <= 64) && (E > 0);

    char* ws = (char*)d_ws;
    if (ok) {
        unsigned* packed = (unsigned*)(ws + off_packed);
        unsigned* gcur   = (unsigned*)(ws + off_gc);
        float*    dinv   = (float*)(ws + off_dinv);
        float*    y      = (float*)(ws + off_y);
        float*    zy     = (float*)(ws + off_zy);

        int scatBlocks = (E + ST - 1) / ST;

        k_init   <<<1, NBMAX, 0, stream>>>(gcur, C, NB);
        k_scatter<<<scatBlocks, SCT, 0, stream>>>(src, dst, E, gcur, packed, C, NB);
        k_deg    <<<NB, BT, 0, stream>>>(packed, gcur, C, x, dinv, y, N);
        k_acc1   <<<NB, BT, 0, stream>>>(packed, gcur, C, y, dinv, W1, b1, W2, zy, N, F);
        k_out    <<<NB, BT, 0, stream>>>(packed, gcur, C, zy, dinv, b2, out, N);
    } else {
        // fallback: verified global-atomic path (needs 12 MB)
        float* dinv = (float*)(ws);
        float* acc1 = (float*)(ws + (size_t)N * 4);
        float* zy   = (float*)(ws + (size_t)N * 8);
        int nodeBlocks = (N + THREADS - 1) / THREADS;
        int edgeBlocks = (E + THREADS - 1) / THREADS;
        if (edgeBlocks > 2048) edgeBlocks = 2048;
        f_zero3<<<2048, THREADS, 0, stream>>>(dinv, acc1, out, N);
        f_deg  <<<edgeBlocks, THREADS, 0, stream>>>(dst, E, dinv);
        f_dinv <<<nodeBlocks, THREADS, 0, stream>>>(dinv, N);
        f_edge1<<<edgeBlocks, THREADS, 0, stream>>>(src, dst, x, dinv, acc1, E);
        f_node2<<<nodeBlocks, THREADS, 0, stream>>>(dinv, acc1, x, W1, b1, W2, zy, N, F);
        f_edge2<<<edgeBlocks, THREADS, 0, stream>>>(src, dst, zy, out, E);
        f_node3<<<nodeBlocks, THREADS, 0, stream>>>(dinv, zy, b2, out, N);
    }
}